// Round 1
// baseline (430.432 us; speedup 1.0000x reference)
//
#include <hip/hip_runtime.h>
#include <math.h>

#define LSEQ 4096
#define CIN  256
#define HID  128
#define O3   384
#define DH   32

#define QKV_N (2 * O3 * LSEQ)   // floats: qkv buffer
// ws layout (floats): [0, QKV_N) = qkv[b][o][l]; [QKV_N, QKV_N+2*HID*LSEQ) = out_raw[b][c][l]

// ---------------- Kernel A: qkv[b,o,l] = sum_c w[o,c] * x[b,c,l] ----------------
__global__ __launch_bounds__(256) void k_qkv(const float* __restrict__ x,
                                             const float* __restrict__ w,
                                             float* __restrict__ qkv) {
    const int tid = threadIdx.x;
    const int l   = blockIdx.x * 512 + tid * 2;
    const int o0  = blockIdx.y * 8;
    const int b   = blockIdx.z;
    const float* xb = x + (size_t)b * CIN * LSEQ + l;
    float a0[8], a1[8];
#pragma unroll
    for (int o = 0; o < 8; ++o) { a0[o] = 0.f; a1[o] = 0.f; }
#pragma unroll 4
    for (int c = 0; c < CIN; ++c) {
        const float2 xv = *(const float2*)(xb + (size_t)c * LSEQ);
#pragma unroll
        for (int o = 0; o < 8; ++o) {
            const float wv = w[(o0 + o) * CIN + c];   // uniform -> scalar load
            a0[o] = fmaf(wv, xv.x, a0[o]);
            a1[o] = fmaf(wv, xv.y, a1[o]);
        }
    }
    float* qb = qkv + (size_t)b * O3 * LSEQ + l;
#pragma unroll
    for (int o = 0; o < 8; ++o)
        *(float2*)(qb + (size_t)(o0 + o) * LSEQ) = make_float2(a0[o], a1[o]);
}

// ------- Kernel B: per-row L2 norm over l for q,k rows; fold SCALE=10 into q -------
__global__ __launch_bounds__(256) void k_norm(float* __restrict__ qkv) {
    const int row = blockIdx.x;            // 0..511
    const int b = row >> 8, o = row & 255; // o<128: q, 128..255: k
    float* p = qkv + ((size_t)b * O3 + o) * LSEQ;
    const int tid = threadIdx.x;
    float ss = 0.f;
#pragma unroll
    for (int r = 0; r < 4; ++r) {
        const float4 v = *(const float4*)(p + (r * 256 + tid) * 4);
        ss += v.x * v.x + v.y * v.y + v.z * v.z + v.w * v.w;
    }
#pragma unroll
    for (int off = 32; off >= 1; off >>= 1) ss += __shfl_xor(ss, off);
    __shared__ float red[4];
    if ((tid & 63) == 0) red[tid >> 6] = ss;
    __syncthreads();
    const float tot = red[0] + red[1] + red[2] + red[3];
    const float scale = (o < HID ? 10.0f : 1.0f) / fmaxf(sqrtf(tot), 1e-12f);
#pragma unroll
    for (int r = 0; r < 4; ++r) {
        float4 v = *(const float4*)(p + (r * 256 + tid) * 4);
        v.x *= scale; v.y *= scale; v.z *= scale; v.w *= scale;
        *(float4*)(p + (r * 256 + tid) * 4) = v;
    }
}

// ---------------- Kernel C: flash attention, f32 vector ----------------
// block: (b, h, iblk) handles BI=64 queries; loops all 4096 keys in BJ=64 tiles.
// threads 256: ti=tid>>4 (4 i each), tj=tid&15 (4 j each in QK; 2 d each in PV)
#define BI 64
#define BJ 64
#define SQ 68
#define SK 68
#define SV 36
#define SP 68

__global__ __launch_bounds__(256) void k_attn(const float* __restrict__ qkv,
                                              float* __restrict__ raw) {
    __shared__ float q_lds[DH][SQ];
    __shared__ float k_lds[DH][SK];
    __shared__ float v_lds[BJ][SV];
    __shared__ float p_lds[BJ][SP];

    const int tid = threadIdx.x;
    const int ti = tid >> 4;   // 0..15
    const int tj = tid & 15;   // 0..15
    const int iblk = blockIdx.x;   // 0..63
    const int h = blockIdx.y, b = blockIdx.z;
    const int i0 = iblk * BI;

    const float* qg = qkv + ((size_t)b * O3 + h * DH) * LSEQ;
    const float* kg = qkv + ((size_t)b * O3 + HID + h * DH) * LSEQ;
    const float* vg = qkv + ((size_t)b * O3 + 2 * HID + h * DH) * LSEQ;

    // stage Q block: q_lds[d][il]
    {
        const int d = tid >> 3;
        const int ib = (tid & 7) * 8;
        const float4 a = *(const float4*)(qg + (size_t)d * LSEQ + i0 + ib);
        const float4 c = *(const float4*)(qg + (size_t)d * LSEQ + i0 + ib + 4);
        *(float4*)&q_lds[d][ib]     = a;
        *(float4*)&q_lds[d][ib + 4] = c;
    }

    float m[4], lsum[4], acc[4][2];
#pragma unroll
    for (int ii = 0; ii < 4; ++ii) { m[ii] = -1e30f; lsum[ii] = 0.f; acc[ii][0] = 0.f; acc[ii][1] = 0.f; }
    __syncthreads();

    for (int j0 = 0; j0 < LSEQ; j0 += BJ) {
        // stage K (row-major) and V (transposed)
        {
            const int d = tid >> 3;
            const int jb = (tid & 7) * 8;
            const float4 ka = *(const float4*)(kg + (size_t)d * LSEQ + j0 + jb);
            const float4 kb = *(const float4*)(kg + (size_t)d * LSEQ + j0 + jb + 4);
            *(float4*)&k_lds[d][jb]     = ka;
            *(float4*)&k_lds[d][jb + 4] = kb;
            const float4 va = *(const float4*)(vg + (size_t)d * LSEQ + j0 + jb);
            const float4 vb = *(const float4*)(vg + (size_t)d * LSEQ + j0 + jb + 4);
            v_lds[jb + 0][d] = va.x; v_lds[jb + 1][d] = va.y;
            v_lds[jb + 2][d] = va.z; v_lds[jb + 3][d] = va.w;
            v_lds[jb + 4][d] = vb.x; v_lds[jb + 5][d] = vb.y;
            v_lds[jb + 6][d] = vb.z; v_lds[jb + 7][d] = vb.w;
        }
        __syncthreads();

        // QK^T: s[4i][4j]
        float s[4][4];
#pragma unroll
        for (int ii = 0; ii < 4; ++ii)
#pragma unroll
            for (int jj = 0; jj < 4; ++jj) s[ii][jj] = 0.f;
#pragma unroll
        for (int d = 0; d < DH; ++d) {
            const float4 qv = *(const float4*)&q_lds[d][ti * 4];
            const float4 kv = *(const float4*)&k_lds[d][tj * 4];
            const float qa[4] = {qv.x, qv.y, qv.z, qv.w};
            const float kb2[4] = {kv.x, kv.y, kv.z, kv.w};
#pragma unroll
            for (int ii = 0; ii < 4; ++ii)
#pragma unroll
                for (int jj = 0; jj < 4; ++jj)
                    s[ii][jj] = fmaf(qa[ii], kb2[jj], s[ii][jj]);
        }

        // online softmax (stats replicated across the 16-lane tj group)
#pragma unroll
        for (int ii = 0; ii < 4; ++ii) {
            float tm = fmaxf(fmaxf(s[ii][0], s[ii][1]), fmaxf(s[ii][2], s[ii][3]));
            tm = fmaxf(tm, __shfl_xor(tm, 1));
            tm = fmaxf(tm, __shfl_xor(tm, 2));
            tm = fmaxf(tm, __shfl_xor(tm, 4));
            tm = fmaxf(tm, __shfl_xor(tm, 8));
            const float mn = fmaxf(m[ii], tm);
            const float rf = __expf(m[ii] - mn);
            m[ii] = mn;
            float ts = 0.f;
#pragma unroll
            for (int jj = 0; jj < 4; ++jj) {
                s[ii][jj] = __expf(s[ii][jj] - mn);
                ts += s[ii][jj];
            }
            ts += __shfl_xor(ts, 1);
            ts += __shfl_xor(ts, 2);
            ts += __shfl_xor(ts, 4);
            ts += __shfl_xor(ts, 8);
            lsum[ii] = lsum[ii] * rf + ts;
            acc[ii][0] *= rf; acc[ii][1] *= rf;
        }

        // write P tile: p_lds[j][i]
#pragma unroll
        for (int jj = 0; jj < 4; ++jj)
            *(float4*)&p_lds[tj * 4 + jj][ti * 4] = make_float4(s[0][jj], s[1][jj], s[2][jj], s[3][jj]);
        __syncthreads();

        // PV: acc[4i][2d] += p[i][j] * v[j][d]
#pragma unroll 16
        for (int j = 0; j < BJ; ++j) {
            const float4 pv = *(const float4*)&p_lds[j][ti * 4];
            const float2 vv = *(const float2*)&v_lds[j][tj * 2];
            acc[0][0] = fmaf(pv.x, vv.x, acc[0][0]); acc[0][1] = fmaf(pv.x, vv.y, acc[0][1]);
            acc[1][0] = fmaf(pv.y, vv.x, acc[1][0]); acc[1][1] = fmaf(pv.y, vv.y, acc[1][1]);
            acc[2][0] = fmaf(pv.z, vv.x, acc[2][0]); acc[2][1] = fmaf(pv.z, vv.y, acc[2][1]);
            acc[3][0] = fmaf(pv.w, vv.x, acc[3][0]); acc[3][1] = fmaf(pv.w, vv.y, acc[3][1]);
        }
        __syncthreads();
    }

    // write out_raw[b][h*32 + (i>>7)][(i&127)*32 + d], d = tj*2 + dd
    const int cl = h * DH + (iblk >> 1);
    const int colbase = (iblk & 1) * 2048;
    float* rp = raw + ((size_t)b * HID + cl) * LSEQ + colbase;
#pragma unroll
    for (int ii = 0; ii < 4; ++ii) {
        const float inv = 1.0f / lsum[ii];
        const int il = ti * 4 + ii;
        *(float2*)(rp + il * 32 + tj * 2) = make_float2(acc[ii][0] * inv, acc[ii][1] * inv);
    }
}

// ---------------- Kernel D: out[b,o,l] = b_out[o] + sum_c w_out[o,c]*raw[b,c,l] ----------------
__global__ __launch_bounds__(256) void k_proj(const float* __restrict__ raw,
                                              const float* __restrict__ w,
                                              const float* __restrict__ bias,
                                              float* __restrict__ out) {
    const int tid = threadIdx.x;
    const int l   = blockIdx.x * 512 + tid * 2;
    const int o0  = blockIdx.y * 8;
    const int b   = blockIdx.z;
    const float* rb = raw + (size_t)b * HID * LSEQ + l;
    float a0[8], a1[8];
#pragma unroll
    for (int o = 0; o < 8; ++o) { a0[o] = 0.f; a1[o] = 0.f; }
#pragma unroll 4
    for (int c = 0; c < HID; ++c) {
        const float2 xv = *(const float2*)(rb + (size_t)c * LSEQ);
#pragma unroll
        for (int o = 0; o < 8; ++o) {
            const float wv = w[(o0 + o) * HID + c];
            a0[o] = fmaf(wv, xv.x, a0[o]);
            a1[o] = fmaf(wv, xv.y, a1[o]);
        }
    }
    float* ob = out + (size_t)b * CIN * LSEQ + l;
#pragma unroll
    for (int o = 0; o < 8; ++o) {
        const float bv = bias[o0 + o];
        *(float2*)(ob + (size_t)(o0 + o) * LSEQ) = make_float2(a0[o] + bv, a1[o] + bv);
    }
}

extern "C" void kernel_launch(void* const* d_in, const int* in_sizes, int n_in,
                              void* d_out, int out_size, void* d_ws, size_t ws_size,
                              hipStream_t stream) {
    const float* x     = (const float*)d_in[0];
    const float* w_qkv = (const float*)d_in[1];
    const float* w_out = (const float*)d_in[2];
    const float* b_out = (const float*)d_in[3];
    float* out = (float*)d_out;
    float* ws  = (float*)d_ws;
    float* qkv = ws;                 // 2*384*4096 floats
    float* raw = ws + QKV_N;         // 2*128*4096 floats

    k_qkv <<<dim3(8, 48, 2),  256, 0, stream>>>(x, w_qkv, qkv);
    k_norm<<<512,             256, 0, stream>>>(qkv);
    k_attn<<<dim3(64, 4, 2),  256, 0, stream>>>(qkv, raw);
    k_proj<<<dim3(8, 32, 2),  256, 0, stream>>>(raw, w_out, b_out, out);
}

// Round 2
// 123.516 us; speedup vs baseline: 3.4848x; 3.4848x over previous
//
#include <hip/hip_runtime.h>
#include <math.h>

#define LSEQ 4096
#define CIN  256
#define HID  128
#define O3   384

typedef float f32x4 __attribute__((ext_vector_type(4)));
typedef short s16x8 __attribute__((ext_vector_type(8)));
typedef short s16x4 __attribute__((ext_vector_type(4)));

typedef const __attribute__((address_space(1))) char* gp_t;
typedef __attribute__((address_space(3))) char* lp_t;

__device__ __forceinline__ short f2bf(float f) {
    union { float f; unsigned u; } c; c.f = f;
    unsigned r = (c.u + 0x7FFFu + ((c.u >> 16) & 1u)) >> 16;
    return (short)r;
}

// ---------------- Kernel A: qkv[b,o,l] = sum_c w[o,c] * x[b,c,l] ----------------
__global__ __launch_bounds__(256) void k_qkv(const float* __restrict__ x,
                                             const float* __restrict__ w,
                                             float* __restrict__ qkv) {
    const int tid = threadIdx.x;
    const int l   = blockIdx.x * 512 + tid * 2;
    const int o0  = blockIdx.y * 8;
    const int b   = blockIdx.z;
    const float* xb = x + (size_t)b * CIN * LSEQ + l;
    float a0[8], a1[8];
#pragma unroll
    for (int o = 0; o < 8; ++o) { a0[o] = 0.f; a1[o] = 0.f; }
#pragma unroll 4
    for (int c = 0; c < CIN; ++c) {
        const float2 xv = *(const float2*)(xb + (size_t)c * LSEQ);
#pragma unroll
        for (int o = 0; o < 8; ++o) {
            const float wv = w[(o0 + o) * CIN + c];
            a0[o] = fmaf(wv, xv.x, a0[o]);
            a1[o] = fmaf(wv, xv.y, a1[o]);
        }
    }
    float* qb = qkv + (size_t)b * O3 * LSEQ + l;
#pragma unroll
    for (int o = 0; o < 8; ++o)
        *(float2*)(qb + (size_t)(o0 + o) * LSEQ) = make_float2(a0[o], a1[o]);
}

// ------- Kernel B: per-row L2 norm over l for q,k rows; fold SCALE=10 into q -------
__global__ __launch_bounds__(256) void k_norm(float* __restrict__ qkv) {
    const int row = blockIdx.x;            // 0..511
    const int b = row >> 8, o = row & 255; // o<128: q, 128..255: k
    float* p = qkv + ((size_t)b * O3 + o) * LSEQ;
    const int tid = threadIdx.x;
    float ss = 0.f;
#pragma unroll
    for (int r = 0; r < 4; ++r) {
        const float4 v = *(const float4*)(p + (r * 256 + tid) * 4);
        ss += v.x * v.x + v.y * v.y + v.z * v.z + v.w * v.w;
    }
#pragma unroll
    for (int off = 32; off >= 1; off >>= 1) ss += __shfl_xor(ss, off);
    __shared__ float red[4];
    if ((tid & 63) == 0) red[tid >> 6] = ss;
    __syncthreads();
    const float tot = red[0] + red[1] + red[2] + red[3];
    const float scale = (o < HID ? 10.0f : 1.0f) / fmaxf(sqrtf(tot), 1e-12f);
#pragma unroll
    for (int r = 0; r < 4; ++r) {
        float4 v = *(const float4*)(p + (r * 256 + tid) * 4);
        v.x *= scale; v.y *= scale; v.z *= scale; v.w *= scale;
        *(float4*)(p + (r * 256 + tid) * 4) = v;
    }
}

// ------- Kernel P: pack bf16 operands -------
// qT[bh][i][d]            (i contiguous rows of 32 d)
// kP[bh][jt][g][jl][e]    : tile image, e=0..7 -> K[j0+jl][g*8+e]
// vP[bh][jt][s][dd][u]    : tile image, 8B group: V[dd][j0 + s*4 + u]
__global__ __launch_bounds__(256) void k_pack(const float* __restrict__ qkv,
                                              short* __restrict__ qT,
                                              short* __restrict__ kP,
                                              short* __restrict__ vP) {
    __shared__ float tile[32][68];
    const int tid = threadIdx.x;
    const int bh = blockIdx.x & 7, ch = blockIdx.x >> 3;
    const int b = bh >> 2, h = bh & 3;
    const int l0 = ch * 64;
    const float* qg = qkv + ((size_t)b * O3 + h * 32) * LSEQ;
    const float* kg = qg + (size_t)HID * LSEQ;
    const float* vg = qg + (size_t)2 * HID * LSEQ;
    const size_t bho = (size_t)bh * (LSEQ * 32);
    const int d = tid >> 3, c8 = (tid & 7) * 8;

    // ---- Q: transpose to qT[i][d] ----
    *(float4*)&tile[d][c8]     = *(const float4*)(qg + (size_t)d * LSEQ + l0 + c8);
    *(float4*)&tile[d][c8 + 4] = *(const float4*)(qg + (size_t)d * LSEQ + l0 + c8 + 4);
    __syncthreads();
    {
        const int i = tid >> 2, dseg = (tid & 3) * 8;
        s16x8 o;
#pragma unroll
        for (int e = 0; e < 8; ++e) o[e] = f2bf(tile[dseg + e][i]);
        *(s16x8*)(qT + bho + (size_t)(l0 + i) * 32 + dseg) = o;
    }
    __syncthreads();
    // ---- K ----
    *(float4*)&tile[d][c8]     = *(const float4*)(kg + (size_t)d * LSEQ + l0 + c8);
    *(float4*)&tile[d][c8 + 4] = *(const float4*)(kg + (size_t)d * LSEQ + l0 + c8 + 4);
    __syncthreads();
    {
        const int gg = tid >> 6, jl = tid & 63;
        s16x8 o;
#pragma unroll
        for (int e = 0; e < 8; ++e) o[e] = f2bf(tile[gg * 8 + e][jl]);
        *(s16x8*)(kP + bho + (size_t)ch * 2048 + gg * 512 + jl * 8) = o;
    }
    __syncthreads();
    // ---- V ----
    *(float4*)&tile[d][c8]     = *(const float4*)(vg + (size_t)d * LSEQ + l0 + c8);
    *(float4*)&tile[d][c8 + 4] = *(const float4*)(vg + (size_t)d * LSEQ + l0 + c8 + 4);
    __syncthreads();
    {
        const int s = tid >> 4, dd = (tid & 15) * 2;
        s16x8 o;
#pragma unroll
        for (int u = 0; u < 4; ++u) {
            o[u]     = f2bf(tile[dd][s * 4 + u]);
            o[4 + u] = f2bf(tile[dd + 1][s * 4 + u]);
        }
        *(s16x8*)(vP + bho + (size_t)ch * 2048 + s * 128 + dd * 4) = o;
    }
}

// ---------------- Kernel C: MFMA flash attention ----------------
// 512 threads = 8 waves, each wave owns 16 queries; BI=128, BJ=64.
#define NJT (LSEQ / 64)

__global__ __launch_bounds__(512) void k_attn(const short* __restrict__ qT,
                                              const short* __restrict__ kP,
                                              const short* __restrict__ vP,
                                              float* __restrict__ raw) {
    __shared__ float4 lds_v[1024];   // 16 KB: 2 buffers x (K 4KB | V 4KB)
    char* lds = (char*)lds_v;
    const int tid = threadIdx.x;
    const int lane = tid & 63, w = tid >> 6;
    const int m = lane & 15, g = lane >> 4;
    const int bh = blockIdx.x & 7, iblk = blockIdx.x >> 3;   // XCD-friendly: same bh -> same XCD
    const int b = bh >> 2, h = bh & 3;
    const size_t bho = (size_t)bh * (LSEQ * 32);
    const int i0 = iblk * 128 + w * 16;

    const s16x8 qf = *(const s16x8*)(qT + bho + (size_t)(i0 + m) * 32 + g * 8);
    const char* kPb = (const char*)(kP + bho);
    const char* vPb = (const char*)(vP + bho);

    float m_run = -1e30f, lsum = 0.f;
    f32x4 acc0 = {0.f, 0.f, 0.f, 0.f}, acc1 = {0.f, 0.f, 0.f, 0.f};
    const f32x4 zeroc = {0.f, 0.f, 0.f, 0.f};

    auto stage = [&](int buf, int jt) {
        const char* src = (tid < 256 ? kPb : vPb) + (size_t)jt * 4096 + (tid & 255) * 16;
        char* dst = lds + buf * 8192 + (tid < 256 ? 0 : 4096) + (w & 3) * 1024;
        __builtin_amdgcn_global_load_lds((gp_t)src, (lp_t)dst, 16, 0, 0);
    };

    stage(0, 0);
    __syncthreads();

    for (int jt = 0; jt < NJT; ++jt) {
        const int buf = jt & 1;
        if (jt + 1 < NJT) stage(buf ^ 1, jt + 1);
        const char* kb = lds + buf * 8192;
        const char* vb = kb + 4096;

        // swapped QK^T: lane holds P[i=i0+m][j = t2*16 + g*4 + r]
        f32x4 st[4];
#pragma unroll
        for (int t2 = 0; t2 < 4; ++t2) {
            const s16x8 kf = *(const s16x8*)(kb + g * 1024 + (t2 * 16 + m) * 16);
            st[t2] = __builtin_amdgcn_mfma_f32_16x16x32_bf16(kf, qf, zeroc, 0, 0, 0);
        }

        // online softmax (row fully on lanes {m, m+16, m+32, m+48})
        float pm = -1e30f;
#pragma unroll
        for (int t2 = 0; t2 < 4; ++t2)
#pragma unroll
            for (int r = 0; r < 4; ++r) pm = fmaxf(pm, st[t2][r]);
        pm = fmaxf(pm, __shfl_xor(pm, 16));
        pm = fmaxf(pm, __shfl_xor(pm, 32));
        const float mn = fmaxf(m_run, pm);
        const float rf = __expf(m_run - mn);
        m_run = mn;
        float ts = 0.f;
        float p[16];
#pragma unroll
        for (int t2 = 0; t2 < 4; ++t2)
#pragma unroll
            for (int r = 0; r < 4; ++r) { const float e = __expf(st[t2][r] - mn); p[t2 * 4 + r] = e; ts += e; }
        ts += __shfl_xor(ts, 16);
        ts += __shfl_xor(ts, 32);
        lsum = lsum * rf + ts;

        s16x8 pa0, pa1;
#pragma unroll
        for (int e = 0; e < 8; ++e) { pa0[e] = f2bf(p[e]); pa1[e] = f2bf(p[8 + e]); }

        // rescale acc (acc row = query g*4+r; stats live on lane g*4+r of group 0)
#pragma unroll
        for (int r = 0; r < 4; ++r) {
            const float rr2 = __shfl(rf, g * 4 + r);
            acc0[r] *= rr2; acc1[r] *= rr2;
        }

        // PV: two K=32 halves (pp), two d-halves (n0)
#pragma unroll
        for (int pp = 0; pp < 2; ++pp) {
            const s16x8 pa = pp ? pa1 : pa0;
#pragma unroll
            for (int n0 = 0; n0 < 2; ++n0) {
                const s16x4 v0 = *(const s16x4*)(vb + (pp * 8 + 0 + g) * 256 + (n0 * 16 + m) * 8);
                const s16x4 v1 = *(const s16x4*)(vb + (pp * 8 + 4 + g) * 256 + (n0 * 16 + m) * 8);
                s16x8 vf;
#pragma unroll
                for (int u = 0; u < 4; ++u) { vf[u] = v0[u]; vf[4 + u] = v1[u]; }
                if (n0 == 0) acc0 = __builtin_amdgcn_mfma_f32_16x16x32_bf16(pa, vf, acc0, 0, 0, 0);
                else         acc1 = __builtin_amdgcn_mfma_f32_16x16x32_bf16(pa, vf, acc1, 0, 0, 0);
            }
        }
        __syncthreads();
    }

    // out_raw[b][h*32 + iblk][ (w*16+g*4+r)*32 + d ]
    float* rr = raw + ((size_t)b * HID + h * 32 + iblk) * LSEQ;
#pragma unroll
    for (int r = 0; r < 4; ++r) {
        const float il = 1.0f / __shfl(lsum, g * 4 + r);
        const int ii = w * 16 + g * 4 + r;
        rr[ii * 32 + m]      = acc0[r] * il;
        rr[ii * 32 + 16 + m] = acc1[r] * il;
    }
}

// ---------------- Kernel D: out[b,o,l] = b_out[o] + sum_c w_out[o,c]*raw[b,c,l] ----------------
__global__ __launch_bounds__(256) void k_proj(const float* __restrict__ raw,
                                              const float* __restrict__ w,
                                              const float* __restrict__ bias,
                                              float* __restrict__ out) {
    const int tid = threadIdx.x;
    const int l   = blockIdx.x * 512 + tid * 2;
    const int o0  = blockIdx.y * 8;
    const int b   = blockIdx.z;
    const float* rb = raw + (size_t)b * HID * LSEQ + l;
    float a0[8], a1[8];
#pragma unroll
    for (int o = 0; o < 8; ++o) { a0[o] = 0.f; a1[o] = 0.f; }
#pragma unroll 4
    for (int c = 0; c < HID; ++c) {
        const float2 xv = *(const float2*)(rb + (size_t)c * LSEQ);
#pragma unroll
        for (int o = 0; o < 8; ++o) {
            const float wv = w[(o0 + o) * HID + c];
            a0[o] = fmaf(wv, xv.x, a0[o]);
            a1[o] = fmaf(wv, xv.y, a1[o]);
        }
    }
    float* ob = out + (size_t)b * CIN * LSEQ + l;
#pragma unroll
    for (int o = 0; o < 8; ++o) {
        const float bv = bias[o0 + o];
        *(float2*)(ob + (size_t)(o0 + o) * LSEQ) = make_float2(a0[o] + bv, a1[o] + bv);
    }
}

extern "C" void kernel_launch(void* const* d_in, const int* in_sizes, int n_in,
                              void* d_out, int out_size, void* d_ws, size_t ws_size,
                              hipStream_t stream) {
    const float* x     = (const float*)d_in[0];
    const float* w_qkv = (const float*)d_in[1];
    const float* w_out = (const float*)d_in[2];
    const float* b_out = (const float*)d_in[3];
    float* out = (float*)d_out;
    float* ws  = (float*)d_ws;

    float* qkv = ws;                         // [0, 3145728) floats
    short* sb  = (short*)(ws + 3145728);     // bf16 region
    short* qT  = sb;                         // 1048576 shorts
    short* kP  = sb + 1048576;
    short* vP  = sb + 2097152;
    float* raw = ws;                         // overlays dead qkv region after pack

    k_qkv <<<dim3(8, 48, 2),  256, 0, stream>>>(x, w_qkv, qkv);
    k_norm<<<512,             256, 0, stream>>>(qkv);
    k_pack<<<512,             256, 0, stream>>>(qkv, qT, kP, vP);
    k_attn<<<256,             512, 0, stream>>>(qT, kP, vP, raw);
    k_proj<<<dim3(8, 32, 2),  256, 0, stream>>>(raw, w_out, b_out, out);
}

// Round 3
// 111.512 us; speedup vs baseline: 3.8600x; 1.1076x over previous
//
#include <hip/hip_runtime.h>
#include <math.h>

#define LSEQ 4096
#define CIN  256
#define HID  128
#define O3   384
#define NSP  2            // split-K factor over key tiles
#define NJT  (LSEQ / 64)  // 64 j-tiles
#define JT_PER_SP (NJT / NSP)

typedef float f32x4 __attribute__((ext_vector_type(4)));
typedef short s16x8 __attribute__((ext_vector_type(8)));
typedef short s16x4 __attribute__((ext_vector_type(4)));

typedef const __attribute__((address_space(1))) char* gp_t;
typedef __attribute__((address_space(3))) char* lp_t;

__device__ __forceinline__ short f2bf(float f) {
    union { float f; unsigned u; } c; c.f = f;
    unsigned r = (c.u + 0x7FFFu + ((c.u >> 16) & 1u)) >> 16;
    return (short)r;
}

__device__ __forceinline__ unsigned cvt_pk_bf16(float lo, float hi) {
    unsigned r;
    asm("v_cvt_pk_bf16_f32 %0, %1, %2" : "=v"(r) : "v"(lo), "v"(hi));
    return r;
}

// ---------------- Kernel A: qkv[b,o,l] = sum_c w[o,c] * x[b,c,l] ----------------
__global__ __launch_bounds__(256) void k_qkv(const float* __restrict__ x,
                                             const float* __restrict__ w,
                                             float* __restrict__ qkv) {
    const int tid = threadIdx.x;
    const int l   = blockIdx.x * 512 + tid * 2;
    const int o0  = blockIdx.y * 8;
    const int b   = blockIdx.z;
    const float* xb = x + (size_t)b * CIN * LSEQ + l;
    float a0[8], a1[8];
#pragma unroll
    for (int o = 0; o < 8; ++o) { a0[o] = 0.f; a1[o] = 0.f; }
#pragma unroll 4
    for (int c = 0; c < CIN; ++c) {
        const float2 xv = *(const float2*)(xb + (size_t)c * LSEQ);
#pragma unroll
        for (int o = 0; o < 8; ++o) {
            const float wv = w[(o0 + o) * CIN + c];
            a0[o] = fmaf(wv, xv.x, a0[o]);
            a1[o] = fmaf(wv, xv.y, a1[o]);
        }
    }
    float* qb = qkv + (size_t)b * O3 * LSEQ + l;
#pragma unroll
    for (int o = 0; o < 8; ++o)
        *(float2*)(qb + (size_t)(o0 + o) * LSEQ) = make_float2(a0[o], a1[o]);
}

// ------- Kernel B: per-row L2 norm over l for q,k rows; fold SCALE=10 into q -------
__global__ __launch_bounds__(256) void k_norm(float* __restrict__ qkv) {
    const int row = blockIdx.x;            // 0..511
    const int b = row >> 8, o = row & 255; // o<128: q, 128..255: k
    float* p = qkv + ((size_t)b * O3 + o) * LSEQ;
    const int tid = threadIdx.x;
    float ss = 0.f;
#pragma unroll
    for (int r = 0; r < 4; ++r) {
        const float4 v = *(const float4*)(p + (r * 256 + tid) * 4);
        ss += v.x * v.x + v.y * v.y + v.z * v.z + v.w * v.w;
    }
#pragma unroll
    for (int off = 32; off >= 1; off >>= 1) ss += __shfl_xor(ss, off);
    __shared__ float red[4];
    if ((tid & 63) == 0) red[tid >> 6] = ss;
    __syncthreads();
    const float tot = red[0] + red[1] + red[2] + red[3];
    const float scale = (o < HID ? 10.0f : 1.0f) / fmaxf(sqrtf(tot), 1e-12f);
#pragma unroll
    for (int r = 0; r < 4; ++r) {
        float4 v = *(const float4*)(p + (r * 256 + tid) * 4);
        v.x *= scale; v.y *= scale; v.z *= scale; v.w *= scale;
        *(float4*)(p + (r * 256 + tid) * 4) = v;
    }
}

// ------- Kernel P: pack bf16 operands (unchanged layouts from R2) -------
__global__ __launch_bounds__(256) void k_pack(const float* __restrict__ qkv,
                                              short* __restrict__ qT,
                                              short* __restrict__ kP,
                                              short* __restrict__ vP) {
    __shared__ float tile[32][68];
    const int tid = threadIdx.x;
    const int bh = blockIdx.x & 7, ch = blockIdx.x >> 3;
    const int b = bh >> 2, h = bh & 3;
    const int l0 = ch * 64;
    const float* qg = qkv + ((size_t)b * O3 + h * 32) * LSEQ;
    const float* kg = qg + (size_t)HID * LSEQ;
    const float* vg = qg + (size_t)2 * HID * LSEQ;
    const size_t bho = (size_t)bh * (LSEQ * 32);
    const int d = tid >> 3, c8 = (tid & 7) * 8;

    // ---- Q: transpose to qT[i][d] ----
    *(float4*)&tile[d][c8]     = *(const float4*)(qg + (size_t)d * LSEQ + l0 + c8);
    *(float4*)&tile[d][c8 + 4] = *(const float4*)(qg + (size_t)d * LSEQ + l0 + c8 + 4);
    __syncthreads();
    {
        const int i = tid >> 2, dseg = (tid & 3) * 8;
        s16x8 o;
#pragma unroll
        for (int e = 0; e < 8; ++e) o[e] = f2bf(tile[dseg + e][i]);
        *(s16x8*)(qT + bho + (size_t)(l0 + i) * 32 + dseg) = o;
    }
    __syncthreads();
    // ---- K ----
    *(float4*)&tile[d][c8]     = *(const float4*)(kg + (size_t)d * LSEQ + l0 + c8);
    *(float4*)&tile[d][c8 + 4] = *(const float4*)(kg + (size_t)d * LSEQ + l0 + c8 + 4);
    __syncthreads();
    {
        const int gg = tid >> 6, jl = tid & 63;
        s16x8 o;
#pragma unroll
        for (int e = 0; e < 8; ++e) o[e] = f2bf(tile[gg * 8 + e][jl]);
        *(s16x8*)(kP + bho + (size_t)ch * 2048 + gg * 512 + jl * 8) = o;
    }
    __syncthreads();
    // ---- V ----
    *(float4*)&tile[d][c8]     = *(const float4*)(vg + (size_t)d * LSEQ + l0 + c8);
    *(float4*)&tile[d][c8 + 4] = *(const float4*)(vg + (size_t)d * LSEQ + l0 + c8 + 4);
    __syncthreads();
    {
        const int s = tid >> 4, dd = (tid & 15) * 2;
        s16x8 o;
#pragma unroll
        for (int u = 0; u < 4; ++u) {
            o[u]     = f2bf(tile[dd][s * 4 + u]);
            o[4 + u] = f2bf(tile[dd + 1][s * 4 + u]);
        }
        *(s16x8*)(vP + bho + (size_t)ch * 2048 + s * 128 + dd * 4) = o;
    }
}

// ---------------- Kernel C: MFMA flash attention, split-K, no online max ----------------
__global__ __launch_bounds__(512) void k_attn(const short* __restrict__ qT,
                                              const short* __restrict__ kP,
                                              const short* __restrict__ vP,
                                              float* __restrict__ pacc,
                                              float* __restrict__ plsum) {
    __shared__ float4 lds_v[1024];   // 16 KB: 2 buffers x (K 4KB | V 4KB)
    char* lds = (char*)lds_v;
    const int tid = threadIdx.x;
    const int lane = tid & 63, w = tid >> 6;
    const int m = lane & 15, g = lane >> 4;
    const int bh = blockIdx.x & 7;           // XCD-friendly: same bh -> same XCD
    const int rest = blockIdx.x >> 3;        // 0..63
    const int iblk = rest & 31, sp = rest >> 5;
    const int b = bh >> 2, h = bh & 3;
    (void)b; (void)h;
    const size_t bho = (size_t)bh * (LSEQ * 32);
    const int i0 = iblk * 128 + w * 16;

    const s16x8 qf = *(const s16x8*)(qT + bho + (size_t)(i0 + m) * 32 + g * 8);
    const char* kPb = (const char*)(kP + bho);
    const char* vPb = (const char*)(vP + bho);

    float lsum = 0.f;
    f32x4 acc0 = {0.f, 0.f, 0.f, 0.f}, acc1 = {0.f, 0.f, 0.f, 0.f};
    const f32x4 zeroc = {0.f, 0.f, 0.f, 0.f};
    const int jt0 = sp * JT_PER_SP;

    auto stage = [&](int buf, int jt) {
        const char* src = (tid < 256 ? kPb : vPb) + (size_t)jt * 4096 + (tid & 255) * 16;
        char* dst = lds + buf * 8192 + (tid < 256 ? 0 : 4096) + (w & 3) * 1024;
        __builtin_amdgcn_global_load_lds((gp_t)src, (lp_t)dst, 16, 0, 0);
    };

    stage(0, jt0);
    __syncthreads();

    for (int t = 0; t < JT_PER_SP; ++t) {
        const int buf = t & 1;
        if (t + 1 < JT_PER_SP) stage(buf ^ 1, jt0 + t + 1);
        const char* kb = lds + buf * 8192;
        const char* vb = kb + 4096;

        // swapped QK^T: lane holds P[i=i0+m][j = t2*16 + g*4 + r]
        f32x4 st[4];
#pragma unroll
        for (int t2 = 0; t2 < 4; ++t2) {
            const s16x8 kf = *(const s16x8*)(kb + g * 1024 + (t2 * 16 + m) * 16);
            st[t2] = __builtin_amdgcn_mfma_f32_16x16x32_bf16(kf, qf, zeroc, 0, 0, 0);
        }

        // softmax numerator, no shift (logits ~ +-0.1; clamp only for safety)
        float p[16];
        float ts = 0.f;
#pragma unroll
        for (int t2 = 0; t2 < 4; ++t2)
#pragma unroll
            for (int r = 0; r < 4; ++r) {
                const float e = __expf(fminf(st[t2][r], 80.f));
                p[t2 * 4 + r] = e;
                ts += e;
            }
        lsum += ts;

        union { unsigned u[4]; s16x8 v; } a0u, a1u;
#pragma unroll
        for (int e = 0; e < 4; ++e) {
            a0u.u[e] = cvt_pk_bf16(p[2 * e],     p[2 * e + 1]);
            a1u.u[e] = cvt_pk_bf16(p[8 + 2 * e], p[9 + 2 * e]);
        }

        // PV: two K=32 halves (pp), two d-halves (n0) — no rescale needed
#pragma unroll
        for (int pp = 0; pp < 2; ++pp) {
            const s16x8 pa = pp ? a1u.v : a0u.v;
#pragma unroll
            for (int n0 = 0; n0 < 2; ++n0) {
                const s16x4 v0 = *(const s16x4*)(vb + (pp * 8 + 0 + g) * 256 + (n0 * 16 + m) * 8);
                const s16x4 v1 = *(const s16x4*)(vb + (pp * 8 + 4 + g) * 256 + (n0 * 16 + m) * 8);
                s16x8 vf;
#pragma unroll
                for (int u = 0; u < 4; ++u) { vf[u] = v0[u]; vf[4 + u] = v1[u]; }
                if (n0 == 0) acc0 = __builtin_amdgcn_mfma_f32_16x16x32_bf16(pa, vf, acc0, 0, 0, 0);
                else         acc1 = __builtin_amdgcn_mfma_f32_16x16x32_bf16(pa, vf, acc1, 0, 0, 0);
            }
        }
        __syncthreads();
    }

    // row sum lives on lanes {m, m+16, m+32, m+48}
    lsum += __shfl_xor(lsum, 16);
    lsum += __shfl_xor(lsum, 32);

    const size_t pb = ((size_t)(bh * 32 + iblk) * NSP + sp) * 128;
    if (g == 0) plsum[pb + w * 16 + m] = lsum;
    float* pa = pacc + (pb + w * 16) * 32;
#pragma unroll
    for (int r = 0; r < 4; ++r) {
        const int ii = g * 4 + r;
        pa[(size_t)ii * 32 + m]      = acc0[r];
        pa[(size_t)ii * 32 + 16 + m] = acc1[r];
    }
}

// ---------------- Kernel E: combine split-K partials -> raw ----------------
__global__ __launch_bounds__(256) void k_comb(const float* __restrict__ pacc,
                                              const float* __restrict__ plsum,
                                              float* __restrict__ raw) {
    const int qt = blockIdx.x;             // bh*32 + iblk
    const int bh = qt >> 5, iblk = qt & 31;
    const int b = bh >> 2, h = bh & 3;
    const int t = threadIdx.x;
    const int ii = t >> 1, dh = (t & 1) * 16;
    const size_t base = (size_t)qt * NSP * 128;
    const float ls = plsum[base + ii] + plsum[base + 128 + ii];
    const float inv = 1.0f / ls;
    const float* p0 = pacc + (base + ii) * 32 + dh;
    const float* p1 = pacc + (base + 128 + ii) * 32 + dh;
    float* rr = raw + ((size_t)b * HID + h * 32 + iblk) * LSEQ + ii * 32 + dh;
#pragma unroll
    for (int u = 0; u < 16; u += 4) {
        const f32x4 a = *(const f32x4*)(p0 + u);
        const f32x4 c = *(const f32x4*)(p1 + u);
        const f32x4 o = (a + c) * inv;
        *(f32x4*)(rr + u) = o;
    }
}

// ---------------- Kernel D: out[b,o,l] = b_out[o] + sum_c w_out[o,c]*raw[b,c,l] ----------------
__global__ __launch_bounds__(256) void k_proj(const float* __restrict__ raw,
                                              const float* __restrict__ w,
                                              const float* __restrict__ bias,
                                              float* __restrict__ out) {
    const int tid = threadIdx.x;
    const int l   = blockIdx.x * 512 + tid * 2;
    const int o0  = blockIdx.y * 8;
    const int b   = blockIdx.z;
    const float* rb = raw + (size_t)b * HID * LSEQ + l;
    float a0[8], a1[8];
#pragma unroll
    for (int o = 0; o < 8; ++o) { a0[o] = 0.f; a1[o] = 0.f; }
#pragma unroll 4
    for (int c = 0; c < HID; ++c) {
        const float2 xv = *(const float2*)(rb + (size_t)c * LSEQ);
#pragma unroll
        for (int o = 0; o < 8; ++o) {
            const float wv = w[(o0 + o) * HID + c];
            a0[o] = fmaf(wv, xv.x, a0[o]);
            a1[o] = fmaf(wv, xv.y, a1[o]);
        }
    }
    float* ob = out + (size_t)b * CIN * LSEQ + l;
#pragma unroll
    for (int o = 0; o < 8; ++o) {
        const float bv = bias[o0 + o];
        *(float2*)(ob + (size_t)(o0 + o) * LSEQ) = make_float2(a0[o] + bv, a1[o] + bv);
    }
}

extern "C" void kernel_launch(void* const* d_in, const int* in_sizes, int n_in,
                              void* d_out, int out_size, void* d_ws, size_t ws_size,
                              hipStream_t stream) {
    const float* x     = (const float*)d_in[0];
    const float* w_qkv = (const float*)d_in[1];
    const float* w_out = (const float*)d_in[2];
    const float* b_out = (const float*)d_in[3];
    float* out = (float*)d_out;
    float* ws  = (float*)d_ws;

    // ws layout (floats):
    //   [0 .. 3145728)        qkv (f32), dead after k_pack; then:
    //     [0 .. 2097152)        pacc  (256 qtiles x 2 sp x 128 q x 32 d)
    //     [2097152 .. 3145728)  raw   (2 x 128 x 4096)
    //   [3145728 .. 4718592)  qT/kP/vP (bf16, 3 x 1048576 shorts)
    //   [4718592 .. 4784128)  plsum (256 x 2 x 128)
    float* qkv   = ws;
    float* pacc  = ws;
    float* raw   = ws + 2097152;
    short* sb    = (short*)(ws + 3145728);
    short* qT    = sb;
    short* kP    = sb + 1048576;
    short* vP    = sb + 2097152;
    float* plsum = ws + 4718592;

    k_qkv <<<dim3(8, 48, 2),  256, 0, stream>>>(x, w_qkv, qkv);
    k_norm<<<512,             256, 0, stream>>>(qkv);
    k_pack<<<512,             256, 0, stream>>>(qkv, qT, kP, vP);
    k_attn<<<512,             512, 0, stream>>>(qT, kP, vP, pacc, plsum);
    k_comb<<<256,             256, 0, stream>>>(pacc, plsum, raw);
    k_proj<<<dim3(8, 32, 2),  256, 0, stream>>>(raw, w_out, b_out, out);
}

// Round 4
// 72.741 us; speedup vs baseline: 5.9173x; 1.5330x over previous
//
#include <hip/hip_runtime.h>
#include <math.h>

#define LSEQ 4096
#define CIN  256
#define HID  128
#define O3   384
#define NSP  4
#define JTPS (64 / NSP)   // j-tiles per split

typedef float f32x4 __attribute__((ext_vector_type(4)));
typedef short s16x8 __attribute__((ext_vector_type(8)));
typedef short s16x4 __attribute__((ext_vector_type(4)));

typedef const __attribute__((address_space(1))) char* gp_t;
typedef __attribute__((address_space(3))) char* lp_t;

__device__ __forceinline__ short f2bf(float f) {
    union { float f; unsigned u; } c; c.f = f;
    unsigned r = (c.u + 0x7FFFu + ((c.u >> 16) & 1u)) >> 16;
    return (short)r;
}

__device__ __forceinline__ unsigned cvt_pk_bf16(float lo, float hi) {
    unsigned r;
    asm("v_cvt_pk_bf16_f32 %0, %1, %2" : "=v"(r) : "v"(lo), "v"(hi));
    return r;
}

__device__ __forceinline__ float exp2_hw(float x) {
    float r;
    asm("v_exp_f32 %0, %1" : "=v"(r) : "v"(x));
    return r;
}

__device__ __forceinline__ float bfbits(unsigned v, int hi) {
    union { unsigned u; float f; } c;
    c.u = hi ? (v & 0xffff0000u) : (v << 16);
    return c.f;
}

// ---- pack_xw: x -> xP (B-fragment image), w_qkv -> wP, w_out -> wP2 (A-fragment images) ----
// xP[((b*8+ct)*4+g)*4096 + l][e] = x[b][ct*32+g*8+e][l]
// wP[((ot*8+ct)*4+g)*16+m][e]   = w_qkv[ot*16+m][ct*32+g*8+e]
// wP2[((ot*4+ct)*4+g)*16+m][e]  = w_out[ot*16+m][ct*32+g*8+e]
__global__ __launch_bounds__(256) void pack_xw(const float* __restrict__ x,
                                               const float* __restrict__ wq,
                                               const float* __restrict__ wo,
                                               short* __restrict__ xP,
                                               short* __restrict__ wP,
                                               short* __restrict__ wP2) {
    const int tid = threadIdx.x;
    if (blockIdx.x >= 1024) {
        const int gid = (blockIdx.x - 1024) * 256 + tid;
        s16x8 o;
        if (gid < 12288) {
            const int m = gid & 15, g = (gid >> 4) & 3, ct = (gid >> 6) & 7;
            const int ot = gid >> 9;
            const float* src = wq + (ot * 16 + m) * 256 + ct * 32 + g * 8;
#pragma unroll
            for (int e = 0; e < 8; ++e) o[e] = f2bf(src[e]);
            *(s16x8*)(wP + (size_t)gid * 8) = o;
        } else {
            const int g2 = gid - 12288;  // 0..4095
            const int m = g2 & 15, g = (g2 >> 4) & 3, ct = (g2 >> 6) & 3;
            const int ot = g2 >> 8;
            const float* src = wo + (ot * 16 + m) * 128 + ct * 32 + g * 8;
#pragma unroll
            for (int e = 0; e < 8; ++e) o[e] = f2bf(src[e]);
            *(s16x8*)(wP2 + (size_t)g2 * 8) = o;
        }
        return;
    }
    __shared__ float tile[32][68];
    const int b = blockIdx.x >> 9, ct = (blockIdx.x >> 6) & 7, lt = blockIdx.x & 63;
    const int c = tid >> 3, l8 = (tid & 7) * 8;
    const float* xb = x + ((size_t)b * CIN + ct * 32 + c) * LSEQ + lt * 64 + l8;
    *(float4*)&tile[c][l8]     = *(const float4*)xb;
    *(float4*)&tile[c][l8 + 4] = *(const float4*)(xb + 4);
    __syncthreads();
    const int g = tid >> 6, l = tid & 63;
    s16x8 o;
#pragma unroll
    for (int e = 0; e < 8; ++e) o[e] = f2bf(tile[g * 8 + e][l]);
    *(s16x8*)(xP + ((size_t)((b * 8 + ct) * 4 + g) * LSEQ + lt * 64 + l) * 8) = o;
}

// ---- mfma_qkv: qkv[b][o][l] = sum_c W[o][c] X[c][l] via 16x16x32 bf16 MFMA ----
__global__ __launch_bounds__(256) void mfma_qkv(const short* __restrict__ xP,
                                                const short* __restrict__ wP,
                                                float* __restrict__ qkv) {
    const int i = blockIdx.x;
    const int slice = i & 31, ot = i >> 5;       // same (b,lq) slice -> same XCD
    const int b = slice >> 4, lq = slice & 15;
    const int tid = threadIdx.x, lane = tid & 63, w = tid >> 6;
    const int m = lane & 15, g = lane >> 4;
    const int l0 = lq * 256 + w * 64;

    s16x8 wA[8];
#pragma unroll
    for (int ct = 0; ct < 8; ++ct)
        wA[ct] = *(const s16x8*)(wP + ((size_t)((ot * 8 + ct) * 4 + g) * 16 + m) * 8);

    f32x4 acc[4];
#pragma unroll
    for (int t = 0; t < 4; ++t) acc[t] = (f32x4){0.f, 0.f, 0.f, 0.f};

#pragma unroll
    for (int ct = 0; ct < 8; ++ct) {
        const size_t bb = (size_t)((b * 8 + ct) * 4 + g) * LSEQ;
#pragma unroll
        for (int t = 0; t < 4; ++t) {
            const s16x8 xf = *(const s16x8*)(xP + (bb + l0 + t * 16 + m) * 8);
            acc[t] = __builtin_amdgcn_mfma_f32_16x16x32_bf16(wA[ct], xf, acc[t], 0, 0, 0);
        }
    }
    float* qb = qkv + ((size_t)b * O3 + ot * 16) * LSEQ;
#pragma unroll
    for (int t = 0; t < 4; ++t)
#pragma unroll
        for (int r = 0; r < 4; ++r)
            qb[(size_t)(4 * g + r) * LSEQ + l0 + t * 16 + m] = acc[t][r];
}

// ---- k_norm: reduce-only; scales[b*256+o] = (q ? 10*log2e : 1) / max(||row||,eps) ----
__global__ __launch_bounds__(256) void k_norm(const float* __restrict__ qkv,
                                              float* __restrict__ scales) {
    const int row = blockIdx.x;            // 0..511
    const int b = row >> 8, o = row & 255;
    const float* p = qkv + ((size_t)b * O3 + o) * LSEQ;
    const int tid = threadIdx.x;
    float ss = 0.f;
#pragma unroll
    for (int r = 0; r < 4; ++r) {
        const float4 v = *(const float4*)(p + (r * 256 + tid) * 4);
        ss += v.x * v.x + v.y * v.y + v.z * v.z + v.w * v.w;
    }
#pragma unroll
    for (int off = 32; off >= 1; off >>= 1) ss += __shfl_xor(ss, off);
    __shared__ float red[4];
    if ((tid & 63) == 0) red[tid >> 6] = ss;
    __syncthreads();
    if (tid == 0) {
        const float tot = red[0] + red[1] + red[2] + red[3];
        const float num = (o < HID) ? 14.4269504088896340736f : 1.0f;  // 10*log2(e)
        scales[row] = num / fmaxf(sqrtf(tot), 1e-12f);
    }
}

// ---- k_pack: qkv f32 -> qT/kP/vP bf16 (scales applied to q,k) ----
__global__ __launch_bounds__(256) void k_pack(const float* __restrict__ qkv,
                                              const float* __restrict__ scales,
                                              short* __restrict__ qT,
                                              short* __restrict__ kP,
                                              short* __restrict__ vP) {
    __shared__ float tile[32][68];
    const int tid = threadIdx.x;
    const int bh = blockIdx.x & 7, ch = blockIdx.x >> 3;
    const int b = bh >> 2, h = bh & 3;
    const int l0 = ch * 64;
    const float* qg = qkv + ((size_t)b * O3 + h * 32) * LSEQ;
    const float* kg = qg + (size_t)HID * LSEQ;
    const float* vg = qg + (size_t)2 * HID * LSEQ;
    const size_t bho = (size_t)bh * (LSEQ * 32);
    const int d = tid >> 3, c8 = (tid & 7) * 8;

    // ---- Q: transpose + scale -> qT[i][d] ----
    *(float4*)&tile[d][c8]     = *(const float4*)(qg + (size_t)d * LSEQ + l0 + c8);
    *(float4*)&tile[d][c8 + 4] = *(const float4*)(qg + (size_t)d * LSEQ + l0 + c8 + 4);
    __syncthreads();
    {
        const int i = tid >> 2, dseg = (tid & 3) * 8;
        const float4 sa = *(const float4*)(scales + b * 256 + h * 32 + dseg);
        const float4 sb = *(const float4*)(scales + b * 256 + h * 32 + dseg + 4);
        const float sc[8] = {sa.x, sa.y, sa.z, sa.w, sb.x, sb.y, sb.z, sb.w};
        s16x8 o;
#pragma unroll
        for (int e = 0; e < 8; ++e) o[e] = f2bf(tile[dseg + e][i] * sc[e]);
        *(s16x8*)(qT + bho + (size_t)(l0 + i) * 32 + dseg) = o;
    }
    __syncthreads();
    // ---- K ----
    *(float4*)&tile[d][c8]     = *(const float4*)(kg + (size_t)d * LSEQ + l0 + c8);
    *(float4*)&tile[d][c8 + 4] = *(const float4*)(kg + (size_t)d * LSEQ + l0 + c8 + 4);
    __syncthreads();
    {
        const int gg = tid >> 6, jl = tid & 63;
        const float4 sa = *(const float4*)(scales + b * 256 + 128 + h * 32 + gg * 8);
        const float4 sb = *(const float4*)(scales + b * 256 + 128 + h * 32 + gg * 8 + 4);
        const float sc[8] = {sa.x, sa.y, sa.z, sa.w, sb.x, sb.y, sb.z, sb.w};
        s16x8 o;
#pragma unroll
        for (int e = 0; e < 8; ++e) o[e] = f2bf(tile[gg * 8 + e][jl] * sc[e]);
        *(s16x8*)(kP + bho + (size_t)ch * 2048 + gg * 512 + jl * 8) = o;
    }
    __syncthreads();
    // ---- V (unscaled) ----
    *(float4*)&tile[d][c8]     = *(const float4*)(vg + (size_t)d * LSEQ + l0 + c8);
    *(float4*)&tile[d][c8 + 4] = *(const float4*)(vg + (size_t)d * LSEQ + l0 + c8 + 4);
    __syncthreads();
    {
        const int s = tid >> 4, dd = (tid & 15) * 2;
        s16x8 o;
#pragma unroll
        for (int u = 0; u < 4; ++u) {
            o[u]     = f2bf(tile[dd][s * 4 + u]);
            o[4 + u] = f2bf(tile[dd + 1][s * 4 + u]);
        }
        *(s16x8*)(vP + bho + (size_t)ch * 2048 + s * 128 + dd * 4) = o;
    }
}

// ---- k_attn: MFMA flash attention, split-K=4, exp2 softmax, bf16 partials ----
__global__ __launch_bounds__(512, 8) void k_attn(const short* __restrict__ qT,
                                                 const short* __restrict__ kP,
                                                 const short* __restrict__ vP,
                                                 unsigned* __restrict__ pacc2,
                                                 float* __restrict__ plsum) {
    __shared__ float4 lds_v[1024];   // 16 KB: 2 buffers x (K 4KB | V 4KB)
    char* lds = (char*)lds_v;
    const int tid = threadIdx.x;
    const int lane = tid & 63, w = tid >> 6;
    const int m = lane & 15, g = lane >> 4;
    const int bh = blockIdx.x & 7;           // XCD-friendly
    const int rest = blockIdx.x >> 3;        // 0..127
    const int iblk = rest & 31, sp = rest >> 5;
    const size_t bho = (size_t)bh * (LSEQ * 32);
    const int i0 = iblk * 128 + w * 16;

    const s16x8 qf = *(const s16x8*)(qT + bho + (size_t)(i0 + m) * 32 + g * 8);
    const char* kPb = (const char*)(kP + bho);
    const char* vPb = (const char*)(vP + bho);

    float lsum = 0.f;
    f32x4 acc0 = {0.f, 0.f, 0.f, 0.f}, acc1 = {0.f, 0.f, 0.f, 0.f};
    const f32x4 zeroc = {0.f, 0.f, 0.f, 0.f};
    const int jt0 = sp * JTPS;

    auto stage = [&](int buf, int jt) {
        const char* src = (tid < 256 ? kPb : vPb) + (size_t)jt * 4096 + (tid & 255) * 16;
        char* dst = lds + buf * 8192 + (tid < 256 ? 0 : 4096) + (w & 3) * 1024;
        __builtin_amdgcn_global_load_lds((gp_t)src, (lp_t)dst, 16, 0, 0);
    };

    stage(0, jt0);
    __syncthreads();

    for (int t = 0; t < JTPS; ++t) {
        const int buf = t & 1;
        if (t + 1 < JTPS) stage(buf ^ 1, jt0 + t + 1);
        const char* kb = lds + buf * 8192;
        const char* vb = kb + 4096;

        // swapped QK^T: lane holds P[i=i0+m][j = t2*16 + g*4 + r] (log2 domain)
        f32x4 st[4];
#pragma unroll
        for (int t2 = 0; t2 < 4; ++t2) {
            const s16x8 kf = *(const s16x8*)(kb + g * 1024 + (t2 * 16 + m) * 16);
            st[t2] = __builtin_amdgcn_mfma_f32_16x16x32_bf16(kf, qf, zeroc, 0, 0, 0);
        }

        float p[16];
        float ts0 = 0.f, ts1 = 0.f, ts2 = 0.f, ts3 = 0.f;
#pragma unroll
        for (int t2 = 0; t2 < 4; ++t2) {
            const float e0 = exp2_hw(st[t2][0]);
            const float e1 = exp2_hw(st[t2][1]);
            const float e2 = exp2_hw(st[t2][2]);
            const float e3 = exp2_hw(st[t2][3]);
            p[t2 * 4 + 0] = e0; p[t2 * 4 + 1] = e1;
            p[t2 * 4 + 2] = e2; p[t2 * 4 + 3] = e3;
            ts0 += e0; ts1 += e1; ts2 += e2; ts3 += e3;
        }
        lsum += (ts0 + ts1) + (ts2 + ts3);

        union { unsigned u[4]; s16x8 v; } a0u, a1u;
#pragma unroll
        for (int e = 0; e < 4; ++e) {
            a0u.u[e] = cvt_pk_bf16(p[2 * e],     p[2 * e + 1]);
            a1u.u[e] = cvt_pk_bf16(p[8 + 2 * e], p[9 + 2 * e]);
        }

#pragma unroll
        for (int pp = 0; pp < 2; ++pp) {
            const s16x8 pa = pp ? a1u.v : a0u.v;
#pragma unroll
            for (int n0 = 0; n0 < 2; ++n0) {
                const s16x4 v0 = *(const s16x4*)(vb + (pp * 8 + 0 + g) * 256 + (n0 * 16 + m) * 8);
                const s16x4 v1 = *(const s16x4*)(vb + (pp * 8 + 4 + g) * 256 + (n0 * 16 + m) * 8);
                s16x8 vf;
#pragma unroll
                for (int u = 0; u < 4; ++u) { vf[u] = v0[u]; vf[4 + u] = v1[u]; }
                if (n0 == 0) acc0 = __builtin_amdgcn_mfma_f32_16x16x32_bf16(pa, vf, acc0, 0, 0, 0);
                else         acc1 = __builtin_amdgcn_mfma_f32_16x16x32_bf16(pa, vf, acc1, 0, 0, 0);
            }
        }
        __syncthreads();
    }

    lsum += __shfl_xor(lsum, 16);
    lsum += __shfl_xor(lsum, 32);

    const int pb = (bh * 32 + iblk) * NSP + sp;
    if (g == 0) plsum[(size_t)pb * 128 + w * 16 + m] = lsum;
    unsigned* pa = pacc2 + ((size_t)pb * 128 + w * 16) * 16;
#pragma unroll
    for (int r = 0; r < 4; ++r)
        pa[(g * 4 + r) * 16 + m] = cvt_pk_bf16(acc0[r], acc1[r]);
}

// ---- k_comb: sum split-K partials, normalize, emit rawP (proj B-fragment image) ----
// rawP[((b*4+ct2)*4+g)*4096 + l][e] = raw[b][ct2*32+g*8+e][l],  l = ii*32+dd
__global__ __launch_bounds__(256) void k_comb(const unsigned* __restrict__ pacc2,
                                              const float* __restrict__ plsum,
                                              short* __restrict__ rawP) {
    const int b = blockIdx.x >> 6, lblk = blockIdx.x & 63;
    const int l0 = lblk * 64;
    const int t = threadIdx.x;
    const int ct2 = t >> 6, g = (t >> 4) & 3, lsub = t & 15;
    const int ii = (l0 + lsub * 4) >> 5;
    const int mm0 = (lsub * 4) & 15;
    const int hi = (lsub >> 2) & 1;

#pragma unroll
    for (int e = 0; e < 8; ++e) {
        const int row0 = (((b * 4 + ct2) * 32) + g * 8 + e) * NSP;
        float ls = 0.f, a0 = 0.f, a1 = 0.f, a2 = 0.f, a3 = 0.f;
#pragma unroll
        for (int sp = 0; sp < NSP; ++sp) {
            const unsigned* pr = pacc2 + ((size_t)(row0 + sp) * 128 + ii) * 16 + mm0;
            const uint4 u = *(const uint4*)pr;
            a0 += bfbits(u.x, hi); a1 += bfbits(u.y, hi);
            a2 += bfbits(u.z, hi); a3 += bfbits(u.w, hi);
            ls += plsum[(size_t)(row0 + sp) * 128 + ii];
        }
        const float inv = 1.0f / ls;
        short* dst = rawP + (((size_t)((b * 4 + ct2) * 4 + g) * LSEQ) + l0 + lsub * 4) * 8 + e;
        dst[0]  = f2bf(a0 * inv);
        dst[8]  = f2bf(a1 * inv);
        dst[16] = f2bf(a2 * inv);
        dst[24] = f2bf(a3 * inv);
    }
}

// ---- mfma_proj: out[b][o][l] = bias[o] + sum_c Wout[o][c] raw[c][l] ----
__global__ __launch_bounds__(256) void mfma_proj(const short* __restrict__ rawP,
                                                 const short* __restrict__ wP2,
                                                 const float* __restrict__ bias,
                                                 float* __restrict__ out) {
    const int i = blockIdx.x;
    const int slice = i & 31, ot = i >> 5;
    const int b = slice >> 4, lq = slice & 15;
    const int tid = threadIdx.x, lane = tid & 63, w = tid >> 6;
    const int m = lane & 15, g = lane >> 4;
    const int l0 = lq * 256 + w * 64;

    s16x8 wA[4];
#pragma unroll
    for (int ct = 0; ct < 4; ++ct)
        wA[ct] = *(const s16x8*)(wP2 + ((size_t)((ot * 4 + ct) * 4 + g) * 16 + m) * 8);

    f32x4 acc[4];
#pragma unroll
    for (int t = 0; t < 4; ++t) acc[t] = (f32x4){0.f, 0.f, 0.f, 0.f};

#pragma unroll
    for (int ct = 0; ct < 4; ++ct) {
        const size_t bb = (size_t)((b * 4 + ct) * 4 + g) * LSEQ;
#pragma unroll
        for (int t = 0; t < 4; ++t) {
            const s16x8 xf = *(const s16x8*)(rawP + (bb + l0 + t * 16 + m) * 8);
            acc[t] = __builtin_amdgcn_mfma_f32_16x16x32_bf16(wA[ct], xf, acc[t], 0, 0, 0);
        }
    }
    float bv[4];
#pragma unroll
    for (int r = 0; r < 4; ++r) bv[r] = bias[ot * 16 + 4 * g + r];
    float* ob = out + ((size_t)b * CIN + ot * 16) * LSEQ;
#pragma unroll
    for (int t = 0; t < 4; ++t)
#pragma unroll
        for (int r = 0; r < 4; ++r)
            ob[(size_t)(4 * g + r) * LSEQ + l0 + t * 16 + m] = acc[t][r] + bv[r];
}

extern "C" void kernel_launch(void* const* d_in, const int* in_sizes, int n_in,
                              void* d_out, int out_size, void* d_ws, size_t ws_size,
                              hipStream_t stream) {
    const float* x     = (const float*)d_in[0];
    const float* w_qkv = (const float*)d_in[1];
    const float* w_out = (const float*)d_in[2];
    const float* b_out = (const float*)d_in[3];
    float* out = (float*)d_out;
    float* ws  = (float*)d_ws;

    // ws layout (f32 units), total 4,784,640 floats (~19.14 MB), liveness-overlaid:
    //   [0 .. 3,145,728)   qkv f32 (steps 2-4); then pacc2 u32 [0..2,097,152),
    //                      rawP bf16 at 2,097,152 (+524,288), plsum at 2,621,440 (+131,072)
    //   [3,145,728 .. 4,194,304)  xP bf16 (steps 1-2); then qT (@3,145,728) + kP (@3,670,016)
    //   [4,194,304 .. 4,718,592)  vP bf16
    //   [4,718,592 .. 4,767,744)  wP bf16
    //   [4,767,744 .. 4,784,128)  wP2 bf16
    //   [4,784,128 .. 4,784,640)  scales f32
    float*    qkv    = ws;
    unsigned* pacc2  = (unsigned*)ws;
    short*    rawP   = (short*)(ws + 2097152);
    float*    plsum  = ws + 2621440;
    short*    xP     = (short*)(ws + 3145728);
    short*    qT     = (short*)(ws + 3145728);
    short*    kP     = (short*)(ws + 3670016);
    short*    vP     = (short*)(ws + 4194304);
    short*    wP     = (short*)(ws + 4718592);
    short*    wP2    = (short*)(ws + 4767744);
    float*    scales = ws + 4784128;

    pack_xw  <<<1088, 256, 0, stream>>>(x, w_qkv, w_out, xP, wP, wP2);
    mfma_qkv <<<768,  256, 0, stream>>>(xP, wP, qkv);
    k_norm   <<<512,  256, 0, stream>>>(qkv, scales);
    k_pack   <<<512,  256, 0, stream>>>(qkv, scales, qT, kP, vP);
    k_attn   <<<1024, 512, 0, stream>>>(qT, kP, vP, pacc2, plsum);
    k_comb   <<<128,  256, 0, stream>>>(pacc2, plsum, rawP);
    mfma_proj<<<512,  256, 0, stream>>>(rawP, wP2, b_out, out);
}

// Round 5
// 67.173 us; speedup vs baseline: 6.4078x; 1.0829x over previous
//
#include <hip/hip_runtime.h>
#include <math.h>

#define LSEQ 4096
#define CIN  256
#define HID  128
#define O3   384
#define NSP  4
#define JTPS (64 / NSP)   // j-tiles per split

typedef float f32x4 __attribute__((ext_vector_type(4)));
typedef short s16x8 __attribute__((ext_vector_type(8)));
typedef short s16x4 __attribute__((ext_vector_type(4)));

typedef const __attribute__((address_space(1))) char* gp_t;
typedef __attribute__((address_space(3))) char* lp_t;

__device__ __forceinline__ short f2bf(float f) {
    union { float f; unsigned u; } c; c.f = f;
    unsigned r = (c.u + 0x7FFFu + ((c.u >> 16) & 1u)) >> 16;
    return (short)r;
}

__device__ __forceinline__ float bf2f(short s) {
    union { unsigned u; float f; } c;
    c.u = ((unsigned)(unsigned short)s) << 16;
    return c.f;
}

__device__ __forceinline__ unsigned cvt_pk_bf16(float lo, float hi) {
    unsigned r;
    asm("v_cvt_pk_bf16_f32 %0, %1, %2" : "=v"(r) : "v"(lo), "v"(hi));
    return r;
}

__device__ __forceinline__ float exp2_hw(float x) {
    float r;
    asm("v_exp_f32 %0, %1" : "=v"(r) : "v"(x));
    return r;
}

__device__ __forceinline__ float bfbits(unsigned v, int hi) {
    union { unsigned u; float f; } c;
    c.u = hi ? (v & 0xffff0000u) : (v << 16);
    return c.f;
}

// ---- pack_xw: x -> xP (B-fragment image), w_qkv -> wP, w_out -> wP2; zero ss ----
__global__ __launch_bounds__(256) void pack_xw(const float* __restrict__ x,
                                               const float* __restrict__ wq,
                                               const float* __restrict__ wo,
                                               short* __restrict__ xP,
                                               short* __restrict__ wP,
                                               short* __restrict__ wP2,
                                               float* __restrict__ ss) {
    const int tid = threadIdx.x;
    if (blockIdx.x >= 1024) {
        if (blockIdx.x == 1024) { ss[tid] = 0.f; ss[256 + tid] = 0.f; }
        const int gid = (blockIdx.x - 1024) * 256 + tid;
        s16x8 o;
        if (gid < 12288) {
            const int m = gid & 15, g = (gid >> 4) & 3, ct = (gid >> 6) & 7;
            const int ot = gid >> 9;
            const float* src = wq + (ot * 16 + m) * 256 + ct * 32 + g * 8;
#pragma unroll
            for (int e = 0; e < 8; ++e) o[e] = f2bf(src[e]);
            *(s16x8*)(wP + (size_t)gid * 8) = o;
        } else {
            const int g2 = gid - 12288;  // 0..4095
            const int m = g2 & 15, g = (g2 >> 4) & 3, ct = (g2 >> 6) & 3;
            const int ot = g2 >> 8;
            const float* src = wo + (ot * 16 + m) * 128 + ct * 32 + g * 8;
#pragma unroll
            for (int e = 0; e < 8; ++e) o[e] = f2bf(src[e]);
            *(s16x8*)(wP2 + (size_t)g2 * 8) = o;
        }
        return;
    }
    __shared__ float tile[32][68];
    const int b = blockIdx.x >> 9, ct = (blockIdx.x >> 6) & 7, lt = blockIdx.x & 63;
    const int c = tid >> 3, l8 = (tid & 7) * 8;
    const float* xb = x + ((size_t)b * CIN + ct * 32 + c) * LSEQ + lt * 64 + l8;
    *(float4*)&tile[c][l8]     = *(const float4*)xb;
    *(float4*)&tile[c][l8 + 4] = *(const float4*)(xb + 4);
    __syncthreads();
    const int g = tid >> 6, l = tid & 63;
    s16x8 o;
#pragma unroll
    for (int e = 0; e < 8; ++e) o[e] = f2bf(tile[g * 8 + e][l]);
    *(s16x8*)(xP + ((size_t)((b * 8 + ct) * 4 + g) * LSEQ + lt * 64 + l) * 8) = o;
}

// ---- mfma_qkv: qkv(bf16)[b][o][l] = sum_c W[o][c] X[c][l]; fused row sum-of-squares ----
__global__ __launch_bounds__(256) void mfma_qkv(const short* __restrict__ xP,
                                                const short* __restrict__ wP,
                                                short* __restrict__ qkv,
                                                float* __restrict__ ss) {
    const int i = blockIdx.x;
    const int slice = i & 31, ot = i >> 5;
    const int b = slice >> 4, lq = slice & 15;
    const int tid = threadIdx.x, lane = tid & 63, w = tid >> 6;
    const int m = lane & 15, g = lane >> 4;
    const int l0 = lq * 256 + w * 64;

    s16x8 wA[8];
#pragma unroll
    for (int ct = 0; ct < 8; ++ct)
        wA[ct] = *(const s16x8*)(wP + ((size_t)((ot * 8 + ct) * 4 + g) * 16 + m) * 8);

    f32x4 acc[4];
#pragma unroll
    for (int t = 0; t < 4; ++t) acc[t] = (f32x4){0.f, 0.f, 0.f, 0.f};

#pragma unroll
    for (int ct = 0; ct < 8; ++ct) {
        const size_t bb = (size_t)((b * 8 + ct) * 4 + g) * LSEQ;
#pragma unroll
        for (int t = 0; t < 4; ++t) {
            const s16x8 xf = *(const s16x8*)(xP + (bb + l0 + t * 16 + m) * 8);
            acc[t] = __builtin_amdgcn_mfma_f32_16x16x32_bf16(wA[ct], xf, acc[t], 0, 0, 0);
        }
    }
    short* qb = qkv + ((size_t)b * O3 + ot * 16) * LSEQ;
#pragma unroll
    for (int t = 0; t < 4; ++t)
#pragma unroll
        for (int r = 0; r < 4; ++r)
            qb[(size_t)(4 * g + r) * LSEQ + l0 + t * 16 + m] = f2bf(acc[t][r]);

    if (ot < 16) {  // q,k rows need the norm
        float s4[4];
#pragma unroll
        for (int r = 0; r < 4; ++r) {
            float s = acc[0][r] * acc[0][r];
#pragma unroll
            for (int t = 1; t < 4; ++t) s = fmaf(acc[t][r], acc[t][r], s);
#pragma unroll
            for (int mk = 1; mk < 16; mk <<= 1) s += __shfl_xor(s, mk);
            s4[r] = s;
        }
        if (m == 0) {
#pragma unroll
            for (int r = 0; r < 4; ++r)
                atomicAdd(ss + b * 256 + ot * 16 + 4 * g + r, s4[r]);
        }
    }
}

// ---- k_pack: qkv bf16 -> qT/kP/vP (scales from ss applied to q,k) ----
// vP fragment-image: group idx t=(pp*4+g)*32+dd -> {V[dd][pp*32+(e>>2)*16+g*4+(e&3)]}
__global__ __launch_bounds__(256) void k_pack(const short* __restrict__ qkv,
                                              const float* __restrict__ ss,
                                              short* __restrict__ qT,
                                              short* __restrict__ kP,
                                              short* __restrict__ vP) {
    __shared__ float tile[32][68];
    const int tid = threadIdx.x;
    const int bh = blockIdx.x & 7, ch = blockIdx.x >> 3;
    const int b = bh >> 2, h = bh & 3;
    const int l0 = ch * 64;
    const short* qg = qkv + ((size_t)b * O3 + h * 32) * LSEQ;
    const short* kg = qg + (size_t)HID * LSEQ;
    const short* vg = qg + (size_t)2 * HID * LSEQ;
    const size_t bho = (size_t)bh * (LSEQ * 32);
    const int d = tid >> 3, c8 = (tid & 7) * 8;

    // ---- Q: transpose + scale -> qT[i][d] ----
    {
        const s16x8 qv = *(const s16x8*)(qg + (size_t)d * LSEQ + l0 + c8);
#pragma unroll
        for (int e = 0; e < 8; ++e) tile[d][c8 + e] = bf2f(qv[e]);
    }
    __syncthreads();
    {
        const int i = tid >> 2, dseg = (tid & 3) * 8;
        s16x8 o;
#pragma unroll
        for (int e = 0; e < 8; ++e) {
            const float sc = 14.4269504088896340736f /
                             fmaxf(sqrtf(ss[b * 256 + h * 32 + dseg + e]), 1e-12f);
            o[e] = f2bf(tile[dseg + e][i] * sc);
        }
        *(s16x8*)(qT + bho + (size_t)(l0 + i) * 32 + dseg) = o;
    }
    __syncthreads();
    // ---- K ----
    {
        const s16x8 kv = *(const s16x8*)(kg + (size_t)d * LSEQ + l0 + c8);
#pragma unroll
        for (int e = 0; e < 8; ++e) tile[d][c8 + e] = bf2f(kv[e]);
    }
    __syncthreads();
    {
        const int gg = tid >> 6, jl = tid & 63;
        s16x8 o;
#pragma unroll
        for (int e = 0; e < 8; ++e) {
            const float sc = 1.0f /
                             fmaxf(sqrtf(ss[b * 256 + 128 + h * 32 + gg * 8 + e]), 1e-12f);
            o[e] = f2bf(tile[gg * 8 + e][jl] * sc);
        }
        *(s16x8*)(kP + bho + (size_t)ch * 2048 + gg * 512 + jl * 8) = o;
    }
    __syncthreads();
    // ---- V (unscaled), PV-fragment image ----
    {
        const s16x8 vv = *(const s16x8*)(vg + (size_t)d * LSEQ + l0 + c8);
#pragma unroll
        for (int e = 0; e < 8; ++e) tile[d][c8 + e] = bf2f(vv[e]);
    }
    __syncthreads();
    {
        const int pp = tid >> 7, g = (tid >> 5) & 3, dd = tid & 31;
        s16x8 o;
#pragma unroll
        for (int e = 0; e < 8; ++e)
            o[e] = f2bf(tile[dd][pp * 32 + ((e >> 2) * 16) + g * 4 + (e & 3)]);
        *(s16x8*)(vP + bho + (size_t)ch * 2048 + tid * 8) = o;
    }
}

// ---- k_attn: MFMA flash attention, split-K=4, exp2 softmax, bf16 partials ----
__global__ __launch_bounds__(512, 8) void k_attn(const short* __restrict__ qT,
                                                 const short* __restrict__ kP,
                                                 const short* __restrict__ vP,
                                                 unsigned* __restrict__ pacc2,
                                                 float* __restrict__ plsum) {
    __shared__ float4 lds_v[1024];   // 16 KB: 2 buffers x (K 4KB | V 4KB)
    char* lds = (char*)lds_v;
    const int tid = threadIdx.x;
    const int lane = tid & 63, w = tid >> 6;
    const int m = lane & 15, g = lane >> 4;
    const int bh = blockIdx.x & 7;           // XCD-friendly
    const int rest = blockIdx.x >> 3;        // 0..127
    const int iblk = rest & 31, sp = rest >> 5;
    const size_t bho = (size_t)bh * (LSEQ * 32);
    const int i0 = iblk * 128 + w * 16;

    const s16x8 qf = *(const s16x8*)(qT + bho + (size_t)(i0 + m) * 32 + g * 8);
    const char* kPb = (const char*)(kP + bho);
    const char* vPb = (const char*)(vP + bho);

    float lsum = 0.f;
    f32x4 acc0 = {0.f, 0.f, 0.f, 0.f}, acc1 = {0.f, 0.f, 0.f, 0.f};
    const f32x4 zeroc = {0.f, 0.f, 0.f, 0.f};
    const int jt0 = sp * JTPS;

    auto stage = [&](int buf, int jt) {
        const char* src = (tid < 256 ? kPb : vPb) + (size_t)jt * 4096 + (tid & 255) * 16;
        char* dst = lds + buf * 8192 + (tid < 256 ? 0 : 4096) + (w & 3) * 1024;
        __builtin_amdgcn_global_load_lds((gp_t)src, (lp_t)dst, 16, 0, 0);
    };

    stage(0, jt0);
    __syncthreads();

    for (int t = 0; t < JTPS; ++t) {
        const int buf = t & 1;
        if (t + 1 < JTPS) stage(buf ^ 1, jt0 + t + 1);
        const char* kb = lds + buf * 8192;
        const char* vb = kb + 4096;

        // swapped QK^T: lane holds P[i=i0+m][j = t2*16 + g*4 + r] (log2 domain)
        f32x4 st[4];
#pragma unroll
        for (int t2 = 0; t2 < 4; ++t2) {
            const s16x8 kf = *(const s16x8*)(kb + g * 1024 + (t2 * 16 + m) * 16);
            st[t2] = __builtin_amdgcn_mfma_f32_16x16x32_bf16(kf, qf, zeroc, 0, 0, 0);
        }

        float p[16];
        float ts0 = 0.f, ts1 = 0.f, ts2 = 0.f, ts3 = 0.f;
#pragma unroll
        for (int t2 = 0; t2 < 4; ++t2) {
            const float e0 = exp2_hw(st[t2][0]);
            const float e1 = exp2_hw(st[t2][1]);
            const float e2 = exp2_hw(st[t2][2]);
            const float e3 = exp2_hw(st[t2][3]);
            p[t2 * 4 + 0] = e0; p[t2 * 4 + 1] = e1;
            p[t2 * 4 + 2] = e2; p[t2 * 4 + 3] = e3;
            ts0 += e0; ts1 += e1; ts2 += e2; ts3 += e3;
        }
        lsum += (ts0 + ts1) + (ts2 + ts3);

        union { unsigned u[4]; s16x8 v; } a0u, a1u;
#pragma unroll
        for (int e = 0; e < 4; ++e) {
            a0u.u[e] = cvt_pk_bf16(p[2 * e],     p[2 * e + 1]);
            a1u.u[e] = cvt_pk_bf16(p[8 + 2 * e], p[9 + 2 * e]);
        }

#pragma unroll
        for (int pp = 0; pp < 2; ++pp) {
            const s16x8 pa = pp ? a1u.v : a0u.v;
#pragma unroll
            for (int n0 = 0; n0 < 2; ++n0) {
                const s16x8 vf = *(const s16x8*)(vb + (pp * 128 + g * 32 + n0 * 16 + m) * 16);
                if (n0 == 0) acc0 = __builtin_amdgcn_mfma_f32_16x16x32_bf16(pa, vf, acc0, 0, 0, 0);
                else         acc1 = __builtin_amdgcn_mfma_f32_16x16x32_bf16(pa, vf, acc1, 0, 0, 0);
            }
        }
        __syncthreads();
    }

    lsum += __shfl_xor(lsum, 16);
    lsum += __shfl_xor(lsum, 32);

    const int pb = (bh * 32 + iblk) * NSP + sp;
    if (g == 0) plsum[(size_t)pb * 128 + w * 16 + m] = lsum;
    unsigned* pa = pacc2 + ((size_t)pb * 128 + w * 16) * 16;
#pragma unroll
    for (int r = 0; r < 4; ++r)
        pa[(g * 4 + r) * 16 + m] = cvt_pk_bf16(acc0[r], acc1[r]);
}

// ---- k_comb: sum split-K partials, normalize, emit rawP (proj B-fragment image) ----
__global__ __launch_bounds__(256) void k_comb(const unsigned* __restrict__ pacc2,
                                              const float* __restrict__ plsum,
                                              short* __restrict__ rawP) {
    const int b = blockIdx.x >> 6, lblk = blockIdx.x & 63;
    const int l0 = lblk * 64;
    const int t = threadIdx.x;
    const int ct2 = t >> 6, g = (t >> 4) & 3, lsub = t & 15;
    const int ii = (l0 + lsub * 4) >> 5;
    const int mm0 = (lsub * 4) & 15;
    const int hi = (lsub >> 2) & 1;

#pragma unroll
    for (int e = 0; e < 8; ++e) {
        const int row0 = (((b * 4 + ct2) * 32) + g * 8 + e) * NSP;
        float ls = 0.f, a0 = 0.f, a1 = 0.f, a2 = 0.f, a3 = 0.f;
#pragma unroll
        for (int sp = 0; sp < NSP; ++sp) {
            const unsigned* pr = pacc2 + ((size_t)(row0 + sp) * 128 + ii) * 16 + mm0;
            const uint4 u = *(const uint4*)pr;
            a0 += bfbits(u.x, hi); a1 += bfbits(u.y, hi);
            a2 += bfbits(u.z, hi); a3 += bfbits(u.w, hi);
            ls += plsum[(size_t)(row0 + sp) * 128 + ii];
        }
        const float inv = 1.0f / ls;
        short* dst = rawP + (((size_t)((b * 4 + ct2) * 4 + g) * LSEQ) + l0 + lsub * 4) * 8 + e;
        dst[0]  = f2bf(a0 * inv);
        dst[8]  = f2bf(a1 * inv);
        dst[16] = f2bf(a2 * inv);
        dst[24] = f2bf(a3 * inv);
    }
}

// ---- mfma_proj: out[b][o][l] = bias[o] + sum_c Wout[o][c] raw[c][l] ----
__global__ __launch_bounds__(256) void mfma_proj(const short* __restrict__ rawP,
                                                 const short* __restrict__ wP2,
                                                 const float* __restrict__ bias,
                                                 float* __restrict__ out) {
    const int i = blockIdx.x;
    const int slice = i & 31, ot = i >> 5;
    const int b = slice >> 4, lq = slice & 15;
    const int tid = threadIdx.x, lane = tid & 63, w = tid >> 6;
    const int m = lane & 15, g = lane >> 4;
    const int l0 = lq * 256 + w * 64;

    s16x8 wA[4];
#pragma unroll
    for (int ct = 0; ct < 4; ++ct)
        wA[ct] = *(const s16x8*)(wP2 + ((size_t)((ot * 4 + ct) * 4 + g) * 16 + m) * 8);

    f32x4 acc[4];
#pragma unroll
    for (int t = 0; t < 4; ++t) acc[t] = (f32x4){0.f, 0.f, 0.f, 0.f};

#pragma unroll
    for (int ct = 0; ct < 4; ++ct) {
        const size_t bb = (size_t)((b * 4 + ct) * 4 + g) * LSEQ;
#pragma unroll
        for (int t = 0; t < 4; ++t) {
            const s16x8 xf = *(const s16x8*)(rawP + (bb + l0 + t * 16 + m) * 8);
            acc[t] = __builtin_amdgcn_mfma_f32_16x16x32_bf16(wA[ct], xf, acc[t], 0, 0, 0);
        }
    }
    float bv[4];
#pragma unroll
    for (int r = 0; r < 4; ++r) bv[r] = bias[ot * 16 + 4 * g + r];
    float* ob = out + ((size_t)b * CIN + ot * 16) * LSEQ;
#pragma unroll
    for (int t = 0; t < 4; ++t)
#pragma unroll
        for (int r = 0; r < 4; ++r)
            ob[(size_t)(4 * g + r) * LSEQ + l0 + t * 16 + m] = acc[t][r] + bv[r];
}

extern "C" void kernel_launch(void* const* d_in, const int* in_sizes, int n_in,
                              void* d_out, int out_size, void* d_ws, size_t ws_size,
                              hipStream_t stream) {
    const float* x     = (const float*)d_in[0];
    const float* w_qkv = (const float*)d_in[1];
    const float* w_out = (const float*)d_in[2];
    const float* b_out = (const float*)d_in[3];
    float* out = (float*)d_out;
    float* ws  = (float*)d_ws;

    // ws layout (f32 units), liveness-overlaid:
    //   [0 .. 2,097,152)          qkv bf16 (uses 786,432) -> pacc2 u32 (k_attn on)
    //   [2,097,152 .. 2,621,440)  rawP bf16
    //   [2,621,440 .. 2,752,512)  plsum f32
    //   [2,752,512 .. 3,801,088)  xP bf16 -> qT (@2,752,512) + kP (@3,276,800)
    //   [3,801,088 .. 4,325,376)  vP bf16
    //   [4,325,376 .. 4,374,528)  wP bf16
    //   [4,374,528 .. 4,390,912)  wP2 bf16
    //   [4,390,912 .. 4,391,424)  ss f32 (512)
    short*    qkv    = (short*)ws;
    unsigned* pacc2  = (unsigned*)ws;
    short*    rawP   = (short*)(ws + 2097152);
    float*    plsum  = ws + 2621440;
    short*    xP     = (short*)(ws + 2752512);
    short*    qT     = (short*)(ws + 2752512);
    short*    kP     = (short*)(ws + 3276800);
    short*    vP     = (short*)(ws + 3801088);
    short*    wP     = (short*)(ws + 4325376);
    short*    wP2    = (short*)(ws + 4374528);
    float*    ss     = ws + 4390912;

    pack_xw  <<<1088, 256, 0, stream>>>(x, w_qkv, w_out, xP, wP, wP2, ss);
    mfma_qkv <<<768,  256, 0, stream>>>(xP, wP, qkv, ss);
    k_pack   <<<512,  256, 0, stream>>>(qkv, ss, qT, kP, vP);
    k_attn   <<<1024, 512, 0, stream>>>(qT, kP, vP, pacc2, plsum);
    k_comb   <<<128,  256, 0, stream>>>(pacc2, plsum, rawP);
    mfma_proj<<<512,  256, 0, stream>>>(rawP, wP2, b_out, out);
}